// Round 11
// baseline (628.511 us; speedup 1.0000x reference)
//
#include <hip/hip_runtime.h>
#include <stdint.h>
#include <stddef.h>

typedef __bf16 bf16;
typedef __bf16 bf16x4 __attribute__((ext_vector_type(4)));
typedef __bf16 bf16x8 __attribute__((ext_vector_type(8)));
typedef float f32x4 __attribute__((ext_vector_type(4)));
typedef float f32x16 __attribute__((ext_vector_type(16)));

#define BNI 0.9999950000374996f  // 1/sqrt(1+1e-5)
#define NROW 240                  // valid rows per block (12 polylines x 20)
#define TOTROW 163840
#define NPOLY 8192

// swizzled act addressing: row-major stride 256 bf16, 16B chunks XOR-swizzled by row
#define AADDR(r, ch) ((r)*256 + ((((ch) ^ ((r)&31)))<<3))

// dynamic LDS layout (bytes)
#define OFF_ACT  0                // 240*512 = 122880 (sAct; rows 0..11 reused as sY)
#define OFF_POOL 122880           // 32*512  = 16384  (pooled tile, rows 0..11 valid)
#define OFF_T2   139264           // 12*256*2 = 6144  (t2, bf16)
#define OFF_VAL  145408           // 12*4 = 48
#define LDS_TOTAL 145456

// ws layout (bf16 elems) — BN-folded weights
#define WS_PRE_W0 0
#define WS_PRE_W1 8192
#define WS_PRE_W2 73728
#define WS_MLP_W0 139264
#define WS_MLP_W1 270336
#define WS_MLP_W2 335872
#define WS_OUT_W0 401408
#define WS_OUT_W1 466944

__device__ __forceinline__ bf16 f2b(float f){
  unsigned int i = __builtin_bit_cast(unsigned int, f);
  unsigned int r = i + 0x7fffu + ((i >> 16) & 1u);
  unsigned short h = (unsigned short)(r >> 16);
  return __builtin_bit_cast(bf16, h);
}
__device__ __forceinline__ float b2f(bf16 x){
  unsigned short u = __builtin_bit_cast(unsigned short, x);
  union { unsigned int i; float f; } v; v.i = ((unsigned int)u) << 16; return v.f;
}
__device__ __forceinline__ bf16x8 ld8f(const float* p, float sc){
  f32x4 a = *(const f32x4*)p;
  f32x4 b = *(const f32x4*)(p + 4);
  bf16x8 r;
  #pragma unroll
  for (int j = 0; j < 4; ++j){ r[j] = f2b(a[j]*sc); r[4+j] = f2b(b[j]*sc); }
  return r;
}

// ---------------- prep: fp32 weights -> bf16 in ws, BN scale folded ----------------
__global__ __launch_bounds__(256)
void prep_kernel(const float* s0, const float* s1, const float* s2, const float* s3,
                 const float* s4, const float* s5, const float* s6, const float* s7,
                 const float* g0, const float* g1, const float* g3, const float* g4,
                 bf16* dst)
{
  const int offs[8] = {WS_PRE_W0, WS_PRE_W1, WS_PRE_W2, WS_MLP_W0,
                       WS_MLP_W1, WS_MLP_W2, WS_OUT_W0, WS_OUT_W1};
  const int sz[8]   = {8192, 65536, 65536, 131072, 65536, 65536, 65536, 65536};
  const int ld[8]   = {32, 256, 256, 512, 256, 256, 256, 256};
  int r = blockIdx.y;
  const float* src = s0;
  if (r == 1) src = s1; else if (r == 2) src = s2; else if (r == 3) src = s3;
  else if (r == 4) src = s4; else if (r == 5) src = s5; else if (r == 6) src = s6;
  else if (r == 7) src = s7;
  const float* gp = (r==0)?g0:(r==1)?g1:(r==3)?g3:(r==4)?g4:nullptr;
  int i = (blockIdx.x*256 + threadIdx.x)*8;
  if (i < sz[r]){
    float sc = gp ? gp[i/ld[r]]*BNI : 1.0f;   // i..i+7 same row (ld % 8 == 0)
    *(bf16x8*)&dst[offs[r] + i] = ld8f(src + i, sc);
  }
}

// transposed epilogue: lane owns act-row `row`; 4 consecutive features per quad
template<int RELU, int MASK, int ADDT2>
__device__ __forceinline__ void epiT(
    const f32x16& acc, int nt, int row, int poly, float mk, bool valid,
    bf16* sAct, const bf16* sT2, const float* bptr, int hi)
{
  #pragma unroll
  for (int q2 = 0; q2 < 4; ++q2){
    int f0 = nt*32 + 8*q2 + 4*hi;
    f32x4 bb = *(const f32x4*)(bptr + f0);
    bf16x4 tv = {};
    if (ADDT2) tv = *(const bf16x4*)&sT2[poly*256 + f0];
    bf16x4 o;
    #pragma unroll
    for (int j = 0; j < 4; ++j){
      float v = acc[4*q2 + j];
      if (ADDT2) v += b2f(tv[j]);
      v += bb[j];
      if (RELU) v = fmaxf(v, 0.0f);
      if (MASK) v *= mk;
      o[j] = f2b(v);
    }
    if (valid)
      *(bf16x4*)&sAct[row*256 + (((nt*4 + q2) ^ (row & 31))<<3) + 4*hi] = o;
  }
}

// barrier-free 256->256 layer: W direct from global (L1-hot), acts own-row via LDS
template<int RELU, int MASK, int ADDT2>
__device__ __forceinline__ void layerT(
    bf16* sAct, const bf16* sT2,
    const bf16* W, int ldK, const float* bptr,
    const int* maskp, int blk, int row, int rowc, int lane32, int hi)
{
  bf16x8 B[16];
  #pragma unroll
  for (int t = 0; t < 16; ++t)
    B[t] = *(const bf16x8*)&sAct[AADDR(rowc, 2*t + hi)];

  float mk = 1.0f;
  if (MASK){
    int g = blk*NROW + row;
    mk = (row < NROW && g < TOTROW && maskp[g]) ? 1.0f : 0.0f;
  }
  const int poly = rowc/20;
  const bool valid = row < NROW;

  #pragma unroll 1
  for (int nt = 0; nt < 8; ++nt){
    const bf16* p = W + (size_t)(nt*32 + lane32)*ldK + 8*hi;
    bf16x8 wf[16];
    #pragma unroll
    for (int t = 0; t < 16; ++t) wf[t] = *(const bf16x8*)(p + 16*t);
    f32x16 acc = {};
    #pragma unroll
    for (int t = 0; t < 16; ++t)
      acc = __builtin_amdgcn_mfma_f32_32x32x16_bf16(wf[t], B[t], acc, 0, 0, 0);
    epiT<RELU,MASK,ADDT2>(acc, nt, row, poly, mk, valid, sAct, sT2, bptr, hi);
  }
}

// pool 20 mask-zeroed rows per polyline -> sPool rows 0..11 (swizzled)
__device__ __forceinline__ void poolT(const bf16* sAct, bf16* sPool, int tid){
  if (tid < 384){
    int poly = tid >> 5, c = tid & 31;
    float m[8];
    bf16x8 v0 = *(const bf16x8*)&sAct[AADDR(poly*20, c)];
    #pragma unroll
    for (int j = 0; j < 8; ++j) m[j] = b2f(v0[j]);
    for (int r = 1; r < 20; ++r){
      bf16x8 v = *(const bf16x8*)&sAct[AADDR(poly*20 + r, c)];
      #pragma unroll
      for (int j = 0; j < 8; ++j) m[j] = fmaxf(m[j], b2f(v[j]));
    }
    bf16x8 o;
    #pragma unroll
    for (int j = 0; j < 8; ++j) o[j] = f2b(m[j]);
    *(bf16x8*)&sPool[AADDR(poly, c)] = o;
  }
}

__global__ __launch_bounds__(512, 2)
void traj_kernel(const float* __restrict__ poly, const int* __restrict__ maskp,
                 const float* pre_b0, const float* pre_b1, const float* pre_bias2,
                 const float* mlp_b0, const float* mlp_b1, const float* mlp_bias2,
                 const float* out_b0, const float* out_b1,
                 const bf16* __restrict__ ws,
                 float* __restrict__ outp)
{
  extern __shared__ char smem[];
  bf16*  sAct   = (bf16*)(smem + OFF_ACT);
  bf16*  sPool  = (bf16*)(smem + OFF_POOL);
  bf16*  sT2    = (bf16*)(smem + OFF_T2);
  float* sValid = (float*)(smem + OFF_VAL);
  bf16*  sY     = sAct;                      // y tile aliases sAct (dead after pool2)

  const int tid = threadIdx.x;
  const int w = tid >> 6, L = tid & 63, lane32 = L & 31, hi = L >> 5;
  const int row  = w*32 + lane32;            // 0..255; valid < 240
  const int rowc = row < NROW ? row : NROW - 1;   // clamp: B-frag reads stay in-bounds
  const int blk = blockIdx.x;

  const bf16* pw0 = ws + WS_PRE_W0;
  const bf16* pw1 = ws + WS_PRE_W1;
  const bf16* pw2 = ws + WS_PRE_W2;
  const bf16* mw0 = ws + WS_MLP_W0;
  const bf16* mw1 = ws + WS_MLP_W1;
  const bf16* mw2 = ws + WS_MLP_W2;
  const bf16* ow0 = ws + WS_OUT_W0;
  const bf16* ow1 = ws + WS_OUT_W1;

  // ---- phase 0: input (240x32 fp32 -> bf16, swizzled; OOB rows zero) ----
  #pragma unroll
  for (int i = 0; i < 2; ++i){
    int id = tid + 512*i;
    if (id < 960){
      int r = id >> 2, c = id & 3;
      int grow = blk*NROW + r;
      bf16x8 v = {};
      if (grow < TOTROW) v = ld8f(poly + (size_t)grow*32 + c*8, 1.0f);
      *(bf16x8*)&sAct[AADDR(r, c)] = v;
    }
  }
  __syncthreads();
  if (tid < 12){
    float v = 0.0f;
    #pragma unroll
    for (int r = 0; r < 20; ++r){
      int g = blk*NROW + tid*20 + r;
      if (g < TOTROW && maskp[g]) v = 1.0f;
    }
    sValid[tid] = v;                         // consumed in out1 (after several barriers)
  }

  // ---- pre0: K=32, transposed, W direct from ws ----
  {
    bf16x8 B0 = *(const bf16x8*)&sAct[AADDR(rowc, hi)];
    bf16x8 B1 = *(const bf16x8*)&sAct[AADDR(rowc, 2 + hi)];
    #pragma unroll 1
    for (int nt = 0; nt < 8; ++nt){
      const bf16* p = pw0 + (size_t)(nt*32 + lane32)*32 + 8*hi;
      bf16x8 w0 = *(const bf16x8*)p;
      bf16x8 w1 = *(const bf16x8*)(p + 16);
      f32x16 acc = {};
      acc = __builtin_amdgcn_mfma_f32_32x32x16_bf16(w0, B0, acc, 0, 0, 0);
      acc = __builtin_amdgcn_mfma_f32_32x32x16_bf16(w1, B1, acc, 0, 0, 0);
      epiT<1,0,0>(acc, nt, row, 0, 1.0f, row < NROW, sAct, sT2, pre_b0, hi);
    }
  }

  // ---- pre1, pre2 (barrier-free) ----
  layerT<1,0,0>(sAct, sT2, pw1, 256, pre_b1,    maskp, blk, row, rowc, lane32, hi);
  layerT<0,1,0>(sAct, sT2, pw2, 256, pre_bias2, maskp, blk, row, rowc, lane32, hi);

  __syncthreads();                    // pre2 done across waves
  poolT(sAct, sPool, tid);
  __syncthreads();                    // pool1 visible

  // ---- t2 = pooled @ mlp_w0'[:,256:]^T : wave w handles nt = w ----
  {
    bf16x8 Bp[16];
    #pragma unroll
    for (int t = 0; t < 16; ++t)
      Bp[t] = *(const bf16x8*)&sPool[AADDR((lane32 < 12 ? lane32 : 0), 2*t + hi)];
    int nt = w;
    const bf16* p = mw0 + (size_t)(nt*32 + lane32)*512 + 256 + 8*hi;
    f32x16 acc = {};
    #pragma unroll
    for (int t = 0; t < 16; ++t){
      bf16x8 wf = *(const bf16x8*)(p + 16*t);
      acc = __builtin_amdgcn_mfma_f32_32x32x16_bf16(wf, Bp[t], acc, 0, 0, 0);
    }
    if (lane32 < 12){
      #pragma unroll
      for (int q2 = 0; q2 < 4; ++q2){
        int f0 = nt*32 + 8*q2 + 4*hi;
        bf16x4 o;
        #pragma unroll
        for (int j = 0; j < 4; ++j) o[j] = f2b(acc[4*q2 + j]);
        *(bf16x4*)&sT2[lane32*256 + f0] = o;
      }
    }
  }
  __syncthreads();                    // sT2 ready

  // ---- mlp0 (x-half + t2), mlp1, mlp2 (barrier-free) ----
  layerT<1,0,1>(sAct, sT2, mw0, 512, mlp_b0,    maskp, blk, row, rowc, lane32, hi);
  layerT<1,0,0>(sAct, sT2, mw1, 256, mlp_b1,    maskp, blk, row, rowc, lane32, hi);
  layerT<0,1,0>(sAct, sT2, mw2, 256, mlp_bias2, maskp, blk, row, rowc, lane32, hi);

  __syncthreads();                    // mlp2 done
  poolT(sAct, sPool, tid);
  __syncthreads();                    // pool2 visible; sAct dead -> sY

  // ---- out0: y = relu(pool2 @ ow0^T + b0) -> sY rows 0..11; wave w: nt = w ----
  {
    bf16x8 Bp[16];
    #pragma unroll
    for (int t = 0; t < 16; ++t)
      Bp[t] = *(const bf16x8*)&sPool[AADDR((lane32 < 12 ? lane32 : 0), 2*t + hi)];
    int nt = w;
    const bf16* p = ow0 + (size_t)(nt*32 + lane32)*256 + 8*hi;
    f32x16 acc = {};
    #pragma unroll
    for (int t = 0; t < 16; ++t){
      bf16x8 wf = *(const bf16x8*)(p + 16*t);
      acc = __builtin_amdgcn_mfma_f32_32x32x16_bf16(wf, Bp[t], acc, 0, 0, 0);
    }
    if (lane32 < 12){
      #pragma unroll
      for (int q2 = 0; q2 < 4; ++q2){
        int f0 = nt*32 + 8*q2 + 4*hi;
        f32x4 bb = *(const f32x4*)(out_b0 + f0);
        bf16x4 o;
        #pragma unroll
        for (int j = 0; j < 4; ++j) o[j] = f2b(fmaxf(acc[4*q2 + j] + bb[j], 0.0f));
        *(bf16x4*)&sY[lane32*256 + (((nt*4 + q2) ^ (lane32 & 31))<<3) + 4*hi] = o;
      }
    }
  }
  __syncthreads();                    // y visible

  // ---- out1: z = (y @ ow1^T + b1) * valid -> global fp32; wave w: nt = w ----
  {
    bf16x8 By[16];
    #pragma unroll
    for (int t = 0; t < 16; ++t)
      By[t] = *(const bf16x8*)&sY[AADDR((lane32 < 12 ? lane32 : 0), 2*t + hi)];
    int nt = w;
    const bf16* p = ow1 + (size_t)(nt*32 + lane32)*256 + 8*hi;
    f32x16 acc = {};
    #pragma unroll
    for (int t = 0; t < 16; ++t){
      bf16x8 wf = *(const bf16x8*)(p + 16*t);
      acc = __builtin_amdgcn_mfma_f32_32x32x16_bf16(wf, By[t], acc, 0, 0, 0);
    }
    int gp = blk*12 + lane32;
    if (lane32 < 12 && gp < NPOLY){
      float vd = sValid[lane32];
      #pragma unroll
      for (int q2 = 0; q2 < 4; ++q2){
        int f0 = nt*32 + 8*q2 + 4*hi;
        f32x4 bb = *(const f32x4*)(out_b1 + f0);
        f32x4 o;
        #pragma unroll
        for (int j = 0; j < 4; ++j) o[j] = (acc[4*q2 + j] + bb[j]) * vd;
        *(f32x4*)&outp[(size_t)gp*256 + f0] = o;
      }
    }
  }
}

extern "C" void kernel_launch(void* const* d_in, const int* in_sizes, int n_in,
                              void* d_out, int out_size, void* d_ws, size_t ws_size,
                              hipStream_t stream)
{
  const float* poly      = (const float*)d_in[0];
  const int*   maskp     = (const int*)  d_in[1];
  const float* pre_w0    = (const float*)d_in[2];
  const float* pre_g0    = (const float*)d_in[3];
  const float* pre_b0    = (const float*)d_in[4];
  const float* pre_w1    = (const float*)d_in[5];
  const float* pre_g1    = (const float*)d_in[6];
  const float* pre_b1    = (const float*)d_in[7];
  const float* pre_w2    = (const float*)d_in[8];
  const float* pre_bias2 = (const float*)d_in[9];
  const float* mlp_w0    = (const float*)d_in[10];
  const float* mlp_g0    = (const float*)d_in[11];
  const float* mlp_b0    = (const float*)d_in[12];
  const float* mlp_w1    = (const float*)d_in[13];
  const float* mlp_g1    = (const float*)d_in[14];
  const float* mlp_b1    = (const float*)d_in[15];
  const float* mlp_w2    = (const float*)d_in[16];
  const float* mlp_bias2 = (const float*)d_in[17];
  const float* out_w0    = (const float*)d_in[18];
  const float* out_b0    = (const float*)d_in[19];
  const float* out_w1    = (const float*)d_in[20];
  const float* out_b1    = (const float*)d_in[21];

  bf16* ws = (bf16*)d_ws;   // 1,064,960 B of ws used

  (void)hipFuncSetAttribute((const void*)&traj_kernel,
                            hipFuncAttributeMaxDynamicSharedMemorySize, LDS_TOTAL);

  prep_kernel<<<dim3(64, 8), dim3(256), 0, stream>>>(
      pre_w0, pre_w1, pre_w2, mlp_w0, mlp_w1, mlp_w2, out_w0, out_w1,
      pre_g0, pre_g1, mlp_g0, mlp_g1, ws);

  traj_kernel<<<dim3(683), dim3(512), LDS_TOTAL, stream>>>(
      poly, maskp,
      pre_b0, pre_b1, pre_bias2,
      mlp_b0, mlp_b1, mlp_bias2,
      out_b0, out_b1,
      ws, (float*)d_out);
}

// Round 12
// 303.456 us; speedup vs baseline: 2.0712x; 2.0712x over previous
//
#include <hip/hip_runtime.h>
#include <stdint.h>
#include <stddef.h>

typedef __bf16 bf16;
typedef __bf16 bf16x4 __attribute__((ext_vector_type(4)));
typedef __bf16 bf16x8 __attribute__((ext_vector_type(8)));
typedef float f32x4 __attribute__((ext_vector_type(4)));
typedef float f32x16 __attribute__((ext_vector_type(16)));

#define BNI 0.9999950000374996f  // 1/sqrt(1+1e-5)
#define NROW 240                  // valid rows per block (12 polylines x 20)
#define TOTROW 163840
#define NPOLY 8192

// swizzled act addressing: row-major stride 256 bf16, 16B chunks XOR-swizzled by row
#define AADDR(r, ch) ((r)*256 + ((((ch) ^ ((r)&31)))<<3))

// dynamic LDS layout (bytes)
#define OFF_ACT  0                // 240*512 = 122880 (sAct; rows 0..11 reused as sY)
#define OFF_WB0  122880           // 16384: weight chunk buf0 (aliased by sPool)
#define OFF_WB1  139264           // 16384: weight chunk buf1
#define OFF_T2   155648           // 12*256*2 = 6144 (t2, bf16)
#define OFF_VAL  161792           // 12*4 = 48
#define LDS_TOTAL 161840

// ws layout (bf16 elems) — BN-folded weights
#define WS_PRE_W0 0
#define WS_PRE_W1 8192
#define WS_PRE_W2 73728
#define WS_MLP_W0 139264
#define WS_MLP_W1 270336
#define WS_MLP_W2 335872
#define WS_OUT_W0 401408
#define WS_OUT_W1 466944

__device__ __forceinline__ bf16 f2b(float f){
  unsigned int i = __builtin_bit_cast(unsigned int, f);
  unsigned int r = i + 0x7fffu + ((i >> 16) & 1u);
  unsigned short h = (unsigned short)(r >> 16);
  return __builtin_bit_cast(bf16, h);
}
__device__ __forceinline__ float b2f(bf16 x){
  unsigned short u = __builtin_bit_cast(unsigned short, x);
  union { unsigned int i; float f; } v; v.i = ((unsigned int)u) << 16; return v.f;
}
__device__ __forceinline__ bf16x8 ld8f(const float* p, float sc){
  f32x4 a = *(const f32x4*)p;
  f32x4 b = *(const f32x4*)(p + 4);
  bf16x8 r;
  #pragma unroll
  for (int j = 0; j < 4; ++j){ r[j] = f2b(a[j]*sc); r[4+j] = f2b(b[j]*sc); }
  return r;
}

// ---------------- prep: fp32 weights -> bf16 in ws, BN scale folded ----------------
__global__ __launch_bounds__(256)
void prep_kernel(const float* s0, const float* s1, const float* s2, const float* s3,
                 const float* s4, const float* s5, const float* s6, const float* s7,
                 const float* g0, const float* g1, const float* g3, const float* g4,
                 bf16* dst)
{
  const int offs[8] = {WS_PRE_W0, WS_PRE_W1, WS_PRE_W2, WS_MLP_W0,
                       WS_MLP_W1, WS_MLP_W2, WS_OUT_W0, WS_OUT_W1};
  const int sz[8]   = {8192, 65536, 65536, 131072, 65536, 65536, 65536, 65536};
  const int ld[8]   = {32, 256, 256, 512, 256, 256, 256, 256};
  int r = blockIdx.y;
  const float* src = s0;
  if (r == 1) src = s1; else if (r == 2) src = s2; else if (r == 3) src = s3;
  else if (r == 4) src = s4; else if (r == 5) src = s5; else if (r == 6) src = s6;
  else if (r == 7) src = s7;
  const float* gp = (r==0)?g0:(r==1)?g1:(r==3)?g3:(r==4)?g4:nullptr;
  int i = (blockIdx.x*256 + threadIdx.x)*8;
  if (i < sz[r]){
    float sc = gp ? gp[i/ld[r]]*BNI : 1.0f;   // i..i+7 same row (ld % 8 == 0)
    *(bf16x8*)&dst[offs[r] + i] = ld8f(src + i, sc);
  }
}

// ---- stage one 32-feature chunk (32 rows x 256 k = 16 KB): global->regs->LDS swizzled
__device__ __forceinline__ void stageLoad32(bf16x8* st, const bf16* W, int ldK, int nt, int tid){
  #pragma unroll
  for (int i = 0; i < 2; ++i){
    int id = tid + 512*i;               // 1024 16B-chunks
    int fr = id >> 5, kc = id & 31;
    st[i] = *(const bf16x8*)(W + (size_t)(nt*32 + fr)*ldK + kc*8);
  }
}
__device__ __forceinline__ void stageStore32(const bf16x8* st, bf16* buf, int tid){
  #pragma unroll
  for (int i = 0; i < 2; ++i){
    int id = tid + 512*i;
    int fr = id >> 5, kc = id & 31;
    *(bf16x8*)&buf[fr*256 + ((kc ^ (fr & 31))<<3)] = st[i];
  }
}

// transposed epilogue: lane owns act-row `row`; 4 consecutive features per quad
template<int RELU, int MASK, int ADDT2>
__device__ __forceinline__ void epiT(
    const f32x16& acc, int nt, int row, int poly, float mk, bool valid,
    bf16* sAct, const bf16* sT2, const float* bptr, int hi)
{
  #pragma unroll
  for (int q2 = 0; q2 < 4; ++q2){
    int f0 = nt*32 + 8*q2 + 4*hi;
    f32x4 bb = *(const f32x4*)(bptr + f0);
    bf16x4 tv = {};
    if (ADDT2) tv = *(const bf16x4*)&sT2[poly*256 + f0];
    bf16x4 o;
    #pragma unroll
    for (int j = 0; j < 4; ++j){
      float v = acc[4*q2 + j];
      if (ADDT2) v += b2f(tv[j]);
      v += bb[j];
      if (RELU) v = fmaxf(v, 0.0f);
      if (MASK) v *= mk;
      o[j] = f2b(v);
    }
    if (valid)
      *(bf16x4*)&sAct[row*256 + (((nt*4 + q2) ^ (row & 31))<<3) + 4*hi] = o;
  }
}

// 256->256 layer: LDS-staged dbuf weight chunks (1 barrier/chunk), transposed MFMA
template<int RELU, int MASK, int ADDT2>
__device__ __forceinline__ void layerT(
    bf16* sAct, bf16* wb0, bf16* wb1, const bf16* sT2,
    const bf16* W, int ldK, const float* bptr,
    const int* maskp, int blk, int row, int rowc, int lane32, int hi, int tid)
{
  bf16x8 B[16];
  #pragma unroll
  for (int t = 0; t < 16; ++t)
    B[t] = *(const bf16x8*)&sAct[AADDR(rowc, 2*t + hi)];   // own-row, intra-wave dep

  float mk = 1.0f;
  if (MASK){
    int g = blk*NROW + row;
    mk = (row < NROW && g < TOTROW && maskp[g]) ? 1.0f : 0.0f;
  }
  const int poly = rowc/20;
  const bool valid = row < NROW;

  bf16x8 st[2];
  stageLoad32(st, W, ldK, 0, tid);
  stageStore32(st, wb0, tid);
  __syncthreads();                       // chunk 0 staged (entry barrier also protects wb reuse)
  #pragma unroll 1
  for (int c = 0; c < 8; ++c){
    const bf16* cur = (c & 1) ? wb1 : wb0;
    bf16* nxt = (c & 1) ? wb0 : wb1;
    if (c < 7) stageLoad32(st, W, ldK, c + 1, tid);   // global loads under compute
    bf16x8 wf[16];
    const bf16* base = cur + lane32*256;
    #pragma unroll
    for (int t = 0; t < 16; ++t)
      wf[t] = *(const bf16x8*)(base + (((2*t + hi) ^ (lane32 & 31))<<3));
    f32x16 acc = {};
    #pragma unroll
    for (int t = 0; t < 16; ++t)
      acc = __builtin_amdgcn_mfma_f32_32x32x16_bf16(wf[t], B[t], acc, 0, 0, 0);
    epiT<RELU,MASK,ADDT2>(acc, c, row, poly, mk, valid, sAct, sT2, bptr, hi);
    if (c < 7) stageStore32(st, nxt, tid);            // other buffer: WAR-safe post-barrier(c-1)
    __syncthreads();                                  // chunk c+1 staged AND compute c done
  }
}

// pool 20 mask-zeroed rows per polyline -> sPool rows 0..11 (swizzled)
__device__ __forceinline__ void poolT(const bf16* sAct, bf16* sPool, int tid){
  if (tid < 384){
    int poly = tid >> 5, c = tid & 31;
    float m[8];
    bf16x8 v0 = *(const bf16x8*)&sAct[AADDR(poly*20, c)];
    #pragma unroll
    for (int j = 0; j < 8; ++j) m[j] = b2f(v0[j]);
    for (int r = 1; r < 20; ++r){
      bf16x8 v = *(const bf16x8*)&sAct[AADDR(poly*20 + r, c)];
      #pragma unroll
      for (int j = 0; j < 8; ++j) m[j] = fmaxf(m[j], b2f(v[j]));
    }
    bf16x8 o;
    #pragma unroll
    for (int j = 0; j < 8; ++j) o[j] = f2b(m[j]);
    *(bf16x8*)&sPool[AADDR(poly, c)] = o;
  }
}

__global__ __launch_bounds__(512, 2)
void traj_kernel(const float* __restrict__ poly, const int* __restrict__ maskp,
                 const float* pre_b0, const float* pre_b1, const float* pre_bias2,
                 const float* mlp_b0, const float* mlp_b1, const float* mlp_bias2,
                 const float* out_b0, const float* out_b1,
                 const bf16* __restrict__ ws,
                 float* __restrict__ outp)
{
  extern __shared__ char smem[];
  bf16*  sAct   = (bf16*)(smem + OFF_ACT);
  bf16*  wb0    = (bf16*)(smem + OFF_WB0);
  bf16*  wb1    = (bf16*)(smem + OFF_WB1);
  bf16*  sT2    = (bf16*)(smem + OFF_T2);
  float* sValid = (float*)(smem + OFF_VAL);
  bf16*  sPool  = wb0;                       // pooled tile aliases wb0 (barrier-separated)
  bf16*  sY     = sAct;                      // y tile aliases sAct (dead after pool2)

  const int tid = threadIdx.x;
  const int w = tid >> 6, L = tid & 63, lane32 = L & 31, hi = L >> 5;
  const int row  = w*32 + lane32;            // 0..255; valid < 240
  const int rowc = row < NROW ? row : NROW - 1;
  const int blk = blockIdx.x;

  const bf16* pw0 = ws + WS_PRE_W0;
  const bf16* pw1 = ws + WS_PRE_W1;
  const bf16* pw2 = ws + WS_PRE_W2;
  const bf16* mw0 = ws + WS_MLP_W0;
  const bf16* mw1 = ws + WS_MLP_W1;
  const bf16* mw2 = ws + WS_MLP_W2;
  const bf16* ow0 = ws + WS_OUT_W0;
  const bf16* ow1 = ws + WS_OUT_W1;

  // ---- phase 0: input (240x32 fp32 -> bf16, swizzled; OOB rows zero) ----
  #pragma unroll
  for (int i = 0; i < 2; ++i){
    int id = tid + 512*i;
    if (id < 960){
      int r = id >> 2, c = id & 3;
      int grow = blk*NROW + r;
      bf16x8 v = {};
      if (grow < TOTROW) v = ld8f(poly + (size_t)grow*32 + c*8, 1.0f);
      *(bf16x8*)&sAct[AADDR(r, c)] = v;
    }
  }
  __syncthreads();
  if (tid < 12){
    float v = 0.0f;
    #pragma unroll
    for (int r = 0; r < 20; ++r){
      int g = blk*NROW + tid*20 + r;
      if (g < TOTROW && maskp[g]) v = 1.0f;
    }
    sValid[tid] = v;                         // consumed in out1 (after several barriers)
  }

  // ---- pre0: K=32, transposed, W direct from ws (tiny) ----
  {
    bf16x8 B0 = *(const bf16x8*)&sAct[AADDR(rowc, hi)];
    bf16x8 B1 = *(const bf16x8*)&sAct[AADDR(rowc, 2 + hi)];
    #pragma unroll 1
    for (int nt = 0; nt < 8; ++nt){
      const bf16* p = pw0 + (size_t)(nt*32 + lane32)*32 + 8*hi;
      bf16x8 w0 = *(const bf16x8*)p;
      bf16x8 w1 = *(const bf16x8*)(p + 16);
      f32x16 acc = {};
      acc = __builtin_amdgcn_mfma_f32_32x32x16_bf16(w0, B0, acc, 0, 0, 0);
      acc = __builtin_amdgcn_mfma_f32_32x32x16_bf16(w1, B1, acc, 0, 0, 0);
      epiT<1,0,0>(acc, nt, row, 0, 1.0f, row < NROW, sAct, sT2, pre_b0, hi);
    }
  }
  __syncthreads();      // pre0 done; wb buffers free for pre1 staging

  // ---- pre1, pre2 (LDS-staged dbuf) ----
  layerT<1,0,0>(sAct, wb0, wb1, sT2, pw1, 256, pre_b1,    maskp, blk, row, rowc, lane32, hi, tid);
  layerT<0,1,0>(sAct, wb0, wb1, sT2, pw2, 256, pre_bias2, maskp, blk, row, rowc, lane32, hi, tid);

  // last layer barrier done: all pre2 writes visible
  poolT(sAct, sPool, tid);
  __syncthreads();                    // pool1 visible

  // ---- t2 = pooled @ mlp_w0'[:,256:]^T : wave w handles nt = w (direct global) ----
  {
    bf16x8 Bp[16];
    #pragma unroll
    for (int t = 0; t < 16; ++t)
      Bp[t] = *(const bf16x8*)&sPool[AADDR((lane32 < 12 ? lane32 : 0), 2*t + hi)];
    int nt = w;
    const bf16* p = mw0 + (size_t)(nt*32 + lane32)*512 + 256 + 8*hi;
    f32x16 acc = {};
    #pragma unroll
    for (int t = 0; t < 16; ++t){
      bf16x8 wf = *(const bf16x8*)(p + 16*t);
      acc = __builtin_amdgcn_mfma_f32_32x32x16_bf16(wf, Bp[t], acc, 0, 0, 0);
    }
    if (lane32 < 12){
      #pragma unroll
      for (int q2 = 0; q2 < 4; ++q2){
        int f0 = nt*32 + 8*q2 + 4*hi;
        bf16x4 o;
        #pragma unroll
        for (int j = 0; j < 4; ++j) o[j] = f2b(acc[4*q2 + j]);
        *(bf16x4*)&sT2[lane32*256 + f0] = o;
      }
    }
  }
  __syncthreads();                    // sT2 ready; sPool(wb0) reads done

  // ---- mlp0 (x-half + t2), mlp1, mlp2 (LDS-staged dbuf) ----
  layerT<1,0,1>(sAct, wb0, wb1, sT2, mw0, 512, mlp_b0,    maskp, blk, row, rowc, lane32, hi, tid);
  layerT<1,0,0>(sAct, wb0, wb1, sT2, mw1, 256, mlp_b1,    maskp, blk, row, rowc, lane32, hi, tid);
  layerT<0,1,0>(sAct, wb0, wb1, sT2, mw2, 256, mlp_bias2, maskp, blk, row, rowc, lane32, hi, tid);

  // last layer barrier done
  poolT(sAct, sPool, tid);
  __syncthreads();                    // pool2 visible; sAct dead -> sY

  // ---- out0: y = relu(pool2 @ ow0^T + b0) -> sY rows 0..11; wave w: nt = w ----
  {
    bf16x8 Bp[16];
    #pragma unroll
    for (int t = 0; t < 16; ++t)
      Bp[t] = *(const bf16x8*)&sPool[AADDR((lane32 < 12 ? lane32 : 0), 2*t + hi)];
    int nt = w;
    const bf16* p = ow0 + (size_t)(nt*32 + lane32)*256 + 8*hi;
    f32x16 acc = {};
    #pragma unroll
    for (int t = 0; t < 16; ++t){
      bf16x8 wf = *(const bf16x8*)(p + 16*t);
      acc = __builtin_amdgcn_mfma_f32_32x32x16_bf16(wf, Bp[t], acc, 0, 0, 0);
    }
    if (lane32 < 12){
      #pragma unroll
      for (int q2 = 0; q2 < 4; ++q2){
        int f0 = nt*32 + 8*q2 + 4*hi;
        f32x4 bb = *(const f32x4*)(out_b0 + f0);
        bf16x4 o;
        #pragma unroll
        for (int j = 0; j < 4; ++j) o[j] = f2b(fmaxf(acc[4*q2 + j] + bb[j], 0.0f));
        *(bf16x4*)&sY[lane32*256 + (((nt*4 + q2) ^ (lane32 & 31))<<3) + 4*hi] = o;
      }
    }
  }
  __syncthreads();                    // y visible

  // ---- out1: z = (y @ ow1^T + b1) * valid -> global fp32; wave w: nt = w ----
  {
    bf16x8 By[16];
    #pragma unroll
    for (int t = 0; t < 16; ++t)
      By[t] = *(const bf16x8*)&sY[AADDR((lane32 < 12 ? lane32 : 0), 2*t + hi)];
    int nt = w;
    const bf16* p = ow1 + (size_t)(nt*32 + lane32)*256 + 8*hi;
    f32x16 acc = {};
    #pragma unroll
    for (int t = 0; t < 16; ++t){
      bf16x8 wf = *(const bf16x8*)(p + 16*t);
      acc = __builtin_amdgcn_mfma_f32_32x32x16_bf16(wf, By[t], acc, 0, 0, 0);
    }
    int gp = blk*12 + lane32;
    if (lane32 < 12 && gp < NPOLY){
      float vd = sValid[lane32];
      #pragma unroll
      for (int q2 = 0; q2 < 4; ++q2){
        int f0 = nt*32 + 8*q2 + 4*hi;
        f32x4 bb = *(const f32x4*)(out_b1 + f0);
        f32x4 o;
        #pragma unroll
        for (int j = 0; j < 4; ++j) o[j] = (acc[4*q2 + j] + bb[j]) * vd;
        *(f32x4*)&outp[(size_t)gp*256 + f0] = o;
      }
    }
  }
}

extern "C" void kernel_launch(void* const* d_in, const int* in_sizes, int n_in,
                              void* d_out, int out_size, void* d_ws, size_t ws_size,
                              hipStream_t stream)
{
  const float* poly      = (const float*)d_in[0];
  const int*   maskp     = (const int*)  d_in[1];
  const float* pre_w0    = (const float*)d_in[2];
  const float* pre_g0    = (const float*)d_in[3];
  const float* pre_b0    = (const float*)d_in[4];
  const float* pre_w1    = (const float*)d_in[5];
  const float* pre_g1    = (const float*)d_in[6];
  const float* pre_b1    = (const float*)d_in[7];
  const float* pre_w2    = (const float*)d_in[8];
  const float* pre_bias2 = (const float*)d_in[9];
  const float* mlp_w0    = (const float*)d_in[10];
  const float* mlp_g0    = (const float*)d_in[11];
  const float* mlp_b0    = (const float*)d_in[12];
  const float* mlp_w1    = (const float*)d_in[13];
  const float* mlp_g1    = (const float*)d_in[14];
  const float* mlp_b1    = (const float*)d_in[15];
  const float* mlp_w2    = (const float*)d_in[16];
  const float* mlp_bias2 = (const float*)d_in[17];
  const float* out_w0    = (const float*)d_in[18];
  const float* out_b0    = (const float*)d_in[19];
  const float* out_w1    = (const float*)d_in[20];
  const float* out_b1    = (const float*)d_in[21];

  bf16* ws = (bf16*)d_ws;   // 1,064,960 B of ws used

  (void)hipFuncSetAttribute((const void*)&traj_kernel,
                            hipFuncAttributeMaxDynamicSharedMemorySize, LDS_TOTAL);

  prep_kernel<<<dim3(64, 8), dim3(256), 0, stream>>>(
      pre_w0, pre_w1, pre_w2, mlp_w0, mlp_w1, mlp_w2, out_w0, out_w1,
      pre_g0, pre_g1, mlp_g0, mlp_g1, ws);

  traj_kernel<<<dim3(683), dim3(512), LDS_TOTAL, stream>>>(
      poly, maskp,
      pre_b0, pre_b1, pre_bias2,
      mlp_b0, mlp_b1, mlp_bias2,
      out_b0, out_b1,
      ws, (float*)d_out);
}